// Round 8
// baseline (179.334 us; speedup 1.0000x reference)
//
#include <hip/hip_runtime.h>
#include <math.h>

#define NN 4096
#define DD 127
#define HH 128
#define OUTD 3
#define NTYPES 6
#define SIM_THRESH 0.9f
#define BN_EPS 1e-5f
#define MROW 4    // rows per block in build_mask
#define NREP 8    // accumulator replicas

typedef unsigned short ushortT;
typedef __attribute__((ext_vector_type(8))) short short8;   // 8 bf16 (4 VGPRs)
typedef __attribute__((ext_vector_type(4))) float f32x4;

// round-to-nearest-even fp32 -> bf16 (bit pattern)
static __device__ inline ushortT f2bf(float f) {
    unsigned u = __float_as_uint(f);
    unsigned r = (u + 0x7fffu + ((u >> 16) & 1u)) >> 16;
    return (ushortT)r;
}
static __device__ inline float bf2f(ushortT w) {
    return __uint_as_float(((unsigned)w) << 16);
}

// ---------------------------------------------------------------------------
// Kernel P: blocks 0..7 convert W (Wl0,Wl1,Wr0,Wr1) to bf16 row-major.
// Blocks 8..263: 16-row strips: xbf row-major + xbfT [128][4096] transposed
// (A-operand for the masked-MFMA agg kernel), fn, histogram, S0 type-sums.
// ---------------------------------------------------------------------------
__global__ __launch_bounds__(256) void prep(
    const float* __restrict__ x_now, const int* __restrict__ sat,
    const float* __restrict__ Wl, const float* __restrict__ Wr,
    ushortT* __restrict__ Wbf, ushortT* __restrict__ xbf,
    ushortT* __restrict__ xbfT, float4* __restrict__ fn,
    int* __restrict__ cnt, float* __restrict__ S0rep)
{
    int t = threadIdx.x;
    if (blockIdx.x < 8) {
        int baseidx = blockIdx.x * 8192;
        #pragma unroll
        for (int it = 0; it < 32; ++it) {
            int idx = baseidx + it * 256 + t;
            float v = (idx < 32768) ? Wl[idx] : Wr[idx - 32768];
            Wbf[idx] = f2bf(v);
        }
        return;
    }

    int sb = blockIdx.x - 8;           // strip 0..255
    int base = sb * 16;
    int rep = sb & (NREP - 1);
    __shared__ int stypes[16];
    __shared__ float xs[16][HH];       // 8 KB strip stage
    int myti = -1;
    if (t < 16) {
        int row = base + t;
        int ti = sat[row]; ti = min(max(ti, 0), NTYPES - 1);
        stypes[t] = ti; myti = ti;
        const float* rp = x_now + (size_t)row * DD;
        float f0 = rp[0], f2 = rp[1], f3 = rp[2];
        float nrm = fmaxf(sqrtf(2.f * f0 * f0 + f2 * f2 + f3 * f3), 1e-12f);
        float inv = 1.f / nrm;
        fn[row] = make_float4(f0 * inv, f0 * inv, f2 * inv, f3 * inv);
    }
    #pragma unroll
    for (int it = 0; it < 8; ++it) {
        int lin = it * 256 + t;        // 0..2047
        int rl = lin >> 7, col = lin & 127;
        int row = base + rl;
        const float* rp = x_now + (size_t)row * DD;
        float v = (col == 0) ? rp[0] : rp[col - 1];
        xs[rl][col] = v;
        xbf[(size_t)row * HH + col] = f2bf(v);
    }
    __syncthreads();
    // transposed bf16 copy: thread t writes 8 rows of column c
    {
        int c = t >> 1, r0 = (t & 1) * 8;
        short8 sv;
        #pragma unroll
        for (int k = 0; k < 8; ++k) sv[k] = (short)f2bf(xs[r0 + k][c]);
        *(short8*)(xbfT + (size_t)c * NN + base + r0) = sv;
    }
    if (t < 64) {
        #pragma unroll
        for (int tt = 0; tt < NTYPES; ++tt) {
            unsigned long long m = __ballot(myti == tt);
            if (t == 0) {
                int c = __popcll(m);
                if (c) atomicAdd(&cnt[rep * NTYPES + tt], c);
            }
        }
    }
    if (t < 128) {
        float acc[NTYPES] = {0.f, 0.f, 0.f, 0.f, 0.f, 0.f};
        for (int r = 0; r < 16; ++r) {
            float v = xs[r][t];
            int tt = stypes[r];
            #pragma unroll
            for (int q = 0; q < NTYPES; ++q) acc[q] += (tt == q) ? v : 0.f;
        }
        #pragma unroll
        for (int q = 0; q < NTYPES; ++q)
            atomicAdd(&S0rep[(rep * NTYPES + q) * HH + t], acc[q]);
    }
}

// ---------------------------------------------------------------------------
// Kernel B: bitmask + degree. R8: instead of row-major mask words, emit a
// j-CONTIGUOUS transposed bit layout maskT[i][W] (bit jj of word W <-> j =
// W*32+jj) via wave ballots, so the agg kernel's MFMA B-fragments (k = 8
// contiguous j per lane) come from ONE word. Original layout had bit b of
// word w <-> j = b*128+w (j-adjacent bits in different words).
// Ballot transpose: bit b of the 64 words held by one wave's lanes ->
// 64-bit ballot = maskT words W=b*4+w01*2 (lo) and +1 (hi).
// ---------------------------------------------------------------------------
__global__ __launch_bounds__(256) void build_mask(
    const float4* __restrict__ fn, const int* __restrict__ sat,
    const int* __restrict__ cnt, unsigned* __restrict__ maskT,
    float* __restrict__ deg)
{
    int i0 = blockIdx.x * MROW;
    int t = threadIdx.x;
    int w = t & 127;
    int half = t >> 7;
    float4 fi[MROW];
    int ti[MROW];
    #pragma unroll
    for (int r = 0; r < MROW; ++r) {
        fi[r] = fn[i0 + r];
        int tt = sat[i0 + r];
        ti[r] = min(max(tt, 0), NTYPES - 1);
    }
    unsigned word[MROW] = {0, 0, 0, 0};
    int bbase = half * 16;
    for (int bb = 0; bb < 16; ++bb) {
        int b = bbase + bb;
        int j = b * 128 + w;
        float4 fj = fn[j];
        int tj = sat[j];
        #pragma unroll
        for (int r = 0; r < MROW; ++r) {
            float dot = fi[r].x * fj.x + fi[r].y * fj.y
                      + fi[r].z * fj.z + fi[r].w * fj.w;
            if (tj != ti[r] && dot > SIM_THRESH) word[r] |= (1u << b);
        }
    }
    __shared__ unsigned wpart[MROW][128];
    if (half == 1) {
        #pragma unroll
        for (int r = 0; r < MROW; ++r) wpart[r][w] = word[r];
    }
    __syncthreads();
    __shared__ int wt[2][MROW];
    if (half == 0) {                   // waves 0,1 fully active (t 0..127)
        int lane = w & 63, w01 = w >> 6;
        unsigned full[MROW];
        int pcs[MROW];
        #pragma unroll
        for (int r = 0; r < MROW; ++r) {
            full[r] = word[r] | wpart[r][w];
            pcs[r] = __popc(full[r]);
        }
        // --- ballot bit-transpose: j = b*128 + w -> maskT word W=j>>5 ---
        #pragma unroll
        for (int r = 0; r < MROW; ++r) {
            unsigned myw = 0;
            for (int b = 0; b < 32; ++b) {
                unsigned long long m = __ballot((full[r] >> b) & 1u);
                if (lane == b)      myw = (unsigned)m;
                if (lane == b + 32) myw = (unsigned)(m >> 32);
            }
            int W = (lane & 31) * 4 + w01 * 2 + (lane >> 5);
            maskT[(size_t)(i0 + r) * 128 + W] = myw;
        }
        // --- popcount reduce for degree ---
        for (int s = 32; s; s >>= 1) {
            #pragma unroll
            for (int r = 0; r < MROW; ++r) pcs[r] += __shfl_down(pcs[r], s);
        }
        if (lane == 0) {
            #pragma unroll
            for (int r = 0; r < MROW; ++r) wt[w01][r] = pcs[r];
        }
    }
    __syncthreads();
    if (t < MROW) {
        int r = t;
        int ctot = 0;
        #pragma unroll
        for (int rr = 0; rr < NREP; ++rr) ctot += cnt[rr * NTYPES + ti[r]];
        float d = (float)(ctot - 1 + wt[0][r] + wt[1][r]);
        deg[i0 + r] = fmaxf(d, 1.0f);
    }
}

// ---------------------------------------------------------------------------
// Kernel A (agg) — REPLACES the scattered gather. m_cross[i][c] =
// sum_j mask[i][j]*h[j][c] as a masked dense MFMA GEMM: A = HT c-rows
// (bf16, streamed sequentially -> L2-friendly, no scattered cold misses),
// B = mask bits unpacked to 0/1 bf16 in registers (k = 8 contiguous j per
// lane = one maskT word). Grid 1024: block (ib,cs) does i-rows ib*16..+15,
// c-cols cs*32..+31; 4 waves split K (1024 j each), LDS cross-wave reduce.
// Epilogue: m = (S_type - self + msum) / deg -> mbf (same math as before).
// ---------------------------------------------------------------------------
__global__ __launch_bounds__(256) void agg(
    const ushortT* __restrict__ HT, const ushortT* __restrict__ hbf,
    const unsigned* __restrict__ maskT, const float* __restrict__ deg,
    const float* __restrict__ S, const int* __restrict__ sat,
    ushortT* __restrict__ mbf)
{
    int t = threadIdx.x;
    int wv = t >> 6, lane = t & 63;
    int p = lane & 15, q = lane >> 4;
    int ib = blockIdx.x >> 2, cs = blockIdx.x & 3;
    int i0 = ib * 16;
    int c0 = cs * 32;

    __shared__ unsigned smask[16][129];       // padded: K-loop reads conflict-free
    __shared__ float red[4][2][64][4];        // 8 KB cross-wave partials
    __shared__ float msum[16][33];            // padded
    __shared__ int stypes[16];

    #pragma unroll
    for (int it = 0; it < 8; ++it) {
        int lin = it * 256 + t;
        int r = lin >> 7, w = lin & 127;
        smask[r][w] = maskT[(size_t)(i0 + r) * 128 + w];
    }
    if (t < 16) {
        int tt = sat[i0 + t];
        stypes[t] = min(max(tt, 0), NTYPES - 1);
    }
    __syncthreads();

    const ushortT* arow0 = HT + (size_t)(c0 + p) * NN + q * 8;
    const ushortT* arow1 = HT + (size_t)(c0 + 16 + p) * NN + q * 8;
    f32x4 acc0 = {0.f, 0.f, 0.f, 0.f};
    f32x4 acc1 = {0.f, 0.f, 0.f, 0.f};
    int sh0 = q * 8;
    int sbase = wv * 32;                      // wave's K-range: 32 steps of 32 j
    #pragma unroll 4
    for (int s = 0; s < 32; ++s) {
        int step = sbase + s;                 // 0..127
        int jbase = step * 32;
        unsigned wm = smask[p][step] >> sh0;  // bits sh0..sh0+7 = this lane's k
        short8 bv;
        #pragma unroll
        for (int jj = 0; jj < 8; ++jj)
            bv[jj] = ((wm >> jj) & 1u) ? (short)0x3F80 : (short)0;
        short8 a0 = *(const short8*)(arow0 + jbase);
        short8 a1 = *(const short8*)(arow1 + jbase);
        acc0 = __builtin_amdgcn_mfma_f32_16x16x32_bf16(a0, bv, acc0, 0, 0, 0);
        acc1 = __builtin_amdgcn_mfma_f32_16x16x32_bf16(a1, bv, acc1, 0, 0, 0);
    }
    #pragma unroll
    for (int rg = 0; rg < 4; ++rg) {
        red[wv][0][lane][rg] = acc0[rg];
        red[wv][1][lane][rg] = acc1[rg];
    }
    __syncthreads();
    if (wv < 2) {
        // wave wv folds c-tile wv: D col = lane&15 -> i, row = q*4+reg -> c
        #pragma unroll
        for (int rg = 0; rg < 4; ++rg) {
            float tot = red[0][wv][lane][rg] + red[1][wv][lane][rg]
                      + red[2][wv][lane][rg] + red[3][wv][lane][rg];
            msum[p][wv * 16 + q * 4 + rg] = tot;
        }
    }
    __syncthreads();

    // epilogue: 512 outputs, 2 per thread
    #pragma unroll
    for (int e = 0; e < 2; ++e) {
        int lin = e * 256 + t;
        int r = lin >> 5, cl = lin & 31;
        int c = c0 + cl;
        int i = i0 + r;
        int ti = stypes[r];
        float Ssum = 0.f;
        #pragma unroll
        for (int rr = 0; rr < NREP; ++rr)
            Ssum += S[(rr * NTYPES + ti) * HH + c];
        float self = bf2f(hbf[(size_t)i * HH + c]);
        float rdeg = 1.f / deg[i];
        float m = (Ssum - self + msum[r][cl]) * rdeg;
        mbf[(size_t)i * HH + c] = f2bf(m);
    }
}

// ---------------------------------------------------------------------------
// Kernel M1 (layer-1 MFMA GEMM, 512 threads / 8 waves). R8: epilogue also
// writes h1bfT [128][4096] (A-operand for layer-2 agg).
// ---------------------------------------------------------------------------
__global__ __launch_bounds__(512) void gemm_l1(
    const ushortT* __restrict__ mbf, const ushortT* __restrict__ hbf,
    const ushortT* __restrict__ Wlbf, const ushortT* __restrict__ Wrbf,
    const float* __restrict__ bl, const int* __restrict__ sat,
    ushortT* __restrict__ houtbf, ushortT* __restrict__ houtbfT,
    float* __restrict__ acc0)
{
    int t = threadIdx.x;
    int wv = t >> 6, lane = t & 63;
    int p = lane & 15, q = lane >> 4;
    int i0 = blockIdx.x * 16;

    __shared__ float sh[16][129];
    __shared__ int stypes[16];
    if (t < 16) {
        int tt = sat[i0 + t];
        stypes[t] = min(max(tt, 0), NTYPES - 1);
    }

    const ushortT* arow_m = mbf + (size_t)(i0 + p) * HH + q * 8;
    const ushortT* arow_h = hbf + (size_t)(i0 + p) * HH + q * 8;
    short8 am[4], ah[4];
    #pragma unroll
    for (int s = 0; s < 4; ++s) {
        am[s] = *(const short8*)(arow_m + s * 32);
        ah[s] = *(const short8*)(arow_h + s * 32);
    }

    int n0 = wv * 16;                 // one n-tile per wave
    const ushortT* brow_l = Wlbf + (size_t)(n0 + p) * HH + q * 8;
    const ushortT* brow_r = Wrbf + (size_t)(n0 + p) * HH + q * 8;
    f32x4 acc = {0.f, 0.f, 0.f, 0.f};
    #pragma unroll
    for (int s = 0; s < 4; ++s) {
        short8 b = *(const short8*)(brow_l + s * 32);
        acc = __builtin_amdgcn_mfma_f32_16x16x32_bf16(am[s], b, acc, 0, 0, 0);
    }
    #pragma unroll
    for (int s = 0; s < 4; ++s) {
        short8 b = *(const short8*)(brow_r + s * 32);
        acc = __builtin_amdgcn_mfma_f32_16x16x32_bf16(ah[s], b, acc, 0, 0, 0);
    }
    int o = n0 + p;                   // D col = lane&15
    float bv = bl[o];
    #pragma unroll
    for (int rg = 0; rg < 4; ++rg) {
        float v = fmaxf(acc[rg] + bv, 0.f);
        sh[q * 4 + rg][o] = v;        // D row = quad*4 + reg
    }
    __syncthreads();

    #pragma unroll
    for (int e = 0; e < 4; ++e) {
        int lin = e * 512 + t;
        int rr = lin >> 7, cc = lin & 127;
        houtbf[(size_t)i0 * HH + lin] = f2bf(sh[rr][cc]);
    }
    // transposed bf16 copy: thread t writes 4 rows of column c
    {
        int c = t >> 2, r0 = (t & 3) * 4;
        ushort4 uv;
        uv.x = f2bf(sh[r0 + 0][c]);
        uv.y = f2bf(sh[r0 + 1][c]);
        uv.z = f2bf(sh[r0 + 2][c]);
        uv.w = f2bf(sh[r0 + 3][c]);
        *(ushort4*)(houtbfT + (size_t)c * NN + i0 + r0) = uv;
    }
    int rep = blockIdx.x & (NREP - 1);
    if (t < HH) {
        float accq[NTYPES] = {0.f, 0.f, 0.f, 0.f, 0.f, 0.f};
        for (int r = 0; r < 16; ++r) {
            float v = sh[r][t];
            int tt = stypes[r];
            #pragma unroll
            for (int qq = 0; qq < NTYPES; ++qq)
                accq[qq] += (tt == qq) ? v : 0.f;
        }
        #pragma unroll
        for (int qq = 0; qq < NTYPES; ++qq)
            atomicAdd(&acc0[(rep * NTYPES + qq) * HH + t], accq[qq]);
    }
}

// ---------------------------------------------------------------------------
// Kernel M2 (layer-2 MFMA GEMM, 512 threads / 8 waves): fp32 h2 + BN stats.
// ---------------------------------------------------------------------------
__global__ __launch_bounds__(512) void gemm_l2(
    const ushortT* __restrict__ mbf, const ushortT* __restrict__ hbf,
    const ushortT* __restrict__ Wlbf, const ushortT* __restrict__ Wrbf,
    const float* __restrict__ bl, float* __restrict__ hout,
    float* __restrict__ acc0, float* __restrict__ acc1)
{
    int t = threadIdx.x;
    int wv = t >> 6, lane = t & 63;
    int p = lane & 15, q = lane >> 4;
    int i0 = blockIdx.x * 16;

    __shared__ float sh[16][129];

    const ushortT* arow_m = mbf + (size_t)(i0 + p) * HH + q * 8;
    const ushortT* arow_h = hbf + (size_t)(i0 + p) * HH + q * 8;
    short8 am[4], ah[4];
    #pragma unroll
    for (int s = 0; s < 4; ++s) {
        am[s] = *(const short8*)(arow_m + s * 32);
        ah[s] = *(const short8*)(arow_h + s * 32);
    }

    int n0 = wv * 16;
    const ushortT* brow_l = Wlbf + (size_t)(n0 + p) * HH + q * 8;
    const ushortT* brow_r = Wrbf + (size_t)(n0 + p) * HH + q * 8;
    f32x4 acc = {0.f, 0.f, 0.f, 0.f};
    #pragma unroll
    for (int s = 0; s < 4; ++s) {
        short8 b = *(const short8*)(brow_l + s * 32);
        acc = __builtin_amdgcn_mfma_f32_16x16x32_bf16(am[s], b, acc, 0, 0, 0);
    }
    #pragma unroll
    for (int s = 0; s < 4; ++s) {
        short8 b = *(const short8*)(brow_r + s * 32);
        acc = __builtin_amdgcn_mfma_f32_16x16x32_bf16(ah[s], b, acc, 0, 0, 0);
    }
    int o = n0 + p;
    float bv = bl[o];
    #pragma unroll
    for (int rg = 0; rg < 4; ++rg) {
        float v = fmaxf(acc[rg] + bv, 0.f);
        sh[q * 4 + rg][o] = v;
    }
    __syncthreads();

    #pragma unroll
    for (int e = 0; e < 4; ++e) {
        int lin = e * 512 + t;
        int rr = lin >> 7, cc = lin & 127;
        hout[(size_t)i0 * HH + lin] = sh[rr][cc];
    }
    int rep = blockIdx.x & (NREP - 1);
    if (t < HH) {
        float s = 0.f, s2 = 0.f;
        for (int r = 0; r < 16; ++r) {
            float v = sh[r][t];
            s += v; s2 += v * v;
        }
        atomicAdd(&acc0[rep * HH + t], s);
        atomicAdd(&acc1[rep * HH + t], s2);
    }
}

// ---------------------------------------------------------------------------
// Kernel F: BN apply + head, one wave per row; sums the NREP stat replicas.
// ---------------------------------------------------------------------------
__global__ __launch_bounds__(256) void finalize(
    const float* __restrict__ h, const float* __restrict__ musum8,
    const float* __restrict__ varsum8, const float* __restrict__ gamma,
    const float* __restrict__ beta, const float* __restrict__ Wo,
    const float* __restrict__ bo, float* __restrict__ out_h,
    float* __restrict__ out_o)
{
    int t = threadIdx.x;
    int wv = t >> 6;
    int lane = t & 63;
    int i = blockIdx.x * 4 + wv;

    float2 mus = {0.f, 0.f}, vas = {0.f, 0.f};
    #pragma unroll
    for (int r = 0; r < NREP; ++r) {
        float2 a = ((const float2*)(musum8 + r * HH))[lane];
        float2 b = ((const float2*)(varsum8 + r * HH))[lane];
        mus.x += a.x; mus.y += a.y;
        vas.x += b.x; vas.y += b.y;
    }
    float2 ga  = ((const float2*)gamma)[lane];
    float2 be  = ((const float2*)beta)[lane];
    float mu0 = mus.x * (1.f / NN), mu1 = mus.y * (1.f / NN);
    float v0 = vas.x * (1.f / NN) - mu0 * mu0;
    float v1 = vas.y * (1.f / NN) - mu1 * mu1;
    float sc0 = ga.x / sqrtf(v0 + BN_EPS), sc1 = ga.y / sqrtf(v1 + BN_EPS);
    float sh0 = be.x - mu0 * sc0, sh1 = be.y - mu1 * sc1;

    float2 hv = ((const float2*)(h + (size_t)i * HH))[lane];
    float2 hb;
    hb.x = hv.x * sc0 + sh0;
    hb.y = hv.y * sc1 + sh1;
    ((float2*)(out_h + (size_t)i * HH))[lane] = hb;

    float2 w0 = ((const float2*)Wo)[lane];
    float2 w1 = ((const float2*)(Wo + HH))[lane];
    float2 w2 = ((const float2*)(Wo + 2 * HH))[lane];
    float p0 = hb.x * w0.x + hb.y * w0.y;
    float p1 = hb.x * w1.x + hb.y * w1.y;
    float p2 = hb.x * w2.x + hb.y * w2.y;
    for (int s = 32; s; s >>= 1) {
        p0 += __shfl_down(p0, s);
        p1 += __shfl_down(p1, s);
        p2 += __shfl_down(p2, s);
    }
    if (lane == 0) {
        out_o[(size_t)i * OUTD + 0] = p0 + bo[0];
        out_o[(size_t)i * OUTD + 1] = p1 + bo[1];
        out_o[(size_t)i * OUTD + 2] = p2 + bo[2];
    }
}

// ---------------------------------------------------------------------------
extern "C" void kernel_launch(void* const* d_in, const int* in_sizes, int n_in,
                              void* d_out, int out_size, void* d_ws, size_t ws_size,
                              hipStream_t stream)
{
    (void)in_sizes; (void)n_in; (void)out_size; (void)ws_size;
    const float* x_now = (const float*)d_in[0];
    const int*   sat   = (const int*)d_in[1];
    const float* Wl    = (const float*)d_in[2];
    const float* bl    = (const float*)d_in[3];
    const float* Wr    = (const float*)d_in[4];
    const float* gamma = (const float*)d_in[5];
    const float* beta  = (const float*)d_in[6];
    const float* Wo    = (const float*)d_in[7];
    const float* bo    = (const float*)d_in[8];

    ushortT* Wbf   = (ushortT*)d_ws;              // 65536 us [Wl0,Wl1,Wr0,Wr1]
    ushortT* x0bf  = Wbf + 65536;                 // 524288 us
    ushortT* x0bfT = x0bf + (size_t)NN * HH;      // 524288 us (x^T)
    ushortT* h1bf  = x0bfT + (size_t)NN * HH;     // 524288 us
    ushortT* h1bfT = h1bf + (size_t)NN * HH;      // 524288 us (h1^T)
    ushortT* mbf   = h1bfT + (size_t)NN * HH;     // 524288 us (both layers)
    float* h2 = (float*)(mbf + (size_t)NN * HH);  // 524288 f
    float4* fn = (float4*)(h2 + (size_t)NN * HH);       // 4096 float4
    unsigned* maskT = (unsigned*)((float*)fn + 4 * NN); // 524288 words
    float* deg = (float*)(maskT + (size_t)NN * 128);    // 4096
    // ---- zeroed accumulator region (one contiguous memset) ----
    int*   cnt   = (int*)(deg + NN);              // NREP*6 (reserve 64)
    float* S0rep = (float*)(cnt + 64);            // 6144
    float* S1rep = S0rep + NREP * NTYPES * HH;    // 6144
    float* mu8   = S1rep + NREP * NTYPES * HH;    // 1024
    float* var8  = mu8 + NREP * HH;               // 1024

    size_t zero_bytes = (64 + 2 * NREP * NTYPES * HH + 2 * NREP * HH)
                        * sizeof(float);
    hipMemsetAsync(cnt, 0, zero_bytes, stream);

    prep<<<264, 256, 0, stream>>>(x_now, sat, Wl, Wr, Wbf, x0bf, x0bfT, fn,
                                  cnt, S0rep);
    build_mask<<<NN / MROW, 256, 0, stream>>>(fn, sat, cnt, maskT, deg);

    // layer 1
    agg<<<(NN / 16) * 4, 256, 0, stream>>>(x0bfT, x0bf, maskT, deg, S0rep,
                                           sat, mbf);
    gemm_l1<<<NN / 16, 512, 0, stream>>>(mbf, x0bf, Wbf, Wbf + 32768, bl, sat,
                                         h1bf, h1bfT, S1rep);

    // layer 2
    agg<<<(NN / 16) * 4, 256, 0, stream>>>(h1bfT, h1bf, maskT, deg, S1rep,
                                           sat, mbf);
    gemm_l2<<<NN / 16, 512, 0, stream>>>(mbf, h1bf, Wbf + 16384, Wbf + 49152,
                                         bl + HH, h2, mu8, var8);

    finalize<<<NN / 4, 256, 0, stream>>>(h2, mu8, var8, gamma, beta, Wo, bo,
                                         (float*)d_out, (float*)d_out + (size_t)NN * HH);
}

// Round 9
// 155.968 us; speedup vs baseline: 1.1498x; 1.1498x over previous
//
#include <hip/hip_runtime.h>
#include <math.h>

#define NN 4096
#define DD 127
#define HH 128
#define OUTD 3
#define NTYPES 6
#define SIM_THRESH 0.9f
#define BN_EPS 1e-5f
#define MROW 4    // rows per block in build_mask
#define NREP 8    // accumulator replicas
// Half-row neighbor list capacity. Half-degree ~ Binomial(1706, 0.05):
// mean 85, sigma 9 -> 256 = 19-sigma bound.
#define LMAXH 256

typedef unsigned short ushortT;
typedef __attribute__((ext_vector_type(8))) short short8;   // 8 bf16 (4 VGPRs)
typedef __attribute__((ext_vector_type(4))) float f32x4;
typedef __attribute__((ext_vector_type(2))) float f32x2;

// round-to-nearest-even fp32 -> bf16 (bit pattern)
static __device__ inline ushortT f2bf(float f) {
    unsigned u = __float_as_uint(f);
    unsigned r = (u + 0x7fffu + ((u >> 16) & 1u)) >> 16;
    return (ushortT)r;
}
static __device__ inline float bflo(unsigned w) { return __uint_as_float(w << 16); }
static __device__ inline float bfhi(unsigned w) { return __uint_as_float(w & 0xffff0000u); }

// bf16-pair unpack + packed f32 accumulate. Same f32 adds in the same order
// as the scalar version -> bit-identical result.
#define BFACC(vv)                                                         \
    {                                                                     \
        f32x2 t0 = {__uint_as_float((vv).x << 16),                        \
                    __uint_as_float((vv).x & 0xffff0000u)};               \
        f32x2 t1 = {__uint_as_float((vv).y << 16),                        \
                    __uint_as_float((vv).y & 0xffff0000u)};               \
        f32x2 t2 = {__uint_as_float((vv).z << 16),                        \
                    __uint_as_float((vv).z & 0xffff0000u)};               \
        f32x2 t3 = {__uint_as_float((vv).w << 16),                        \
                    __uint_as_float((vv).w & 0xffff0000u)};               \
        acc2[0] += t0; acc2[1] += t1; acc2[2] += t2; acc2[3] += t3;       \
    }

// ---------------------------------------------------------------------------
// Kernel P: blocks 0..7 convert W (Wl0,Wl1,Wr0,Wr1) to bf16 row-major.
// Blocks 8..263: 16-row strips: xbf, fn, type histogram, S0 type-sums.
// ---------------------------------------------------------------------------
__global__ __launch_bounds__(256) void prep(
    const float* __restrict__ x_now, const int* __restrict__ sat,
    const float* __restrict__ Wl, const float* __restrict__ Wr,
    ushortT* __restrict__ Wbf, ushortT* __restrict__ xbf,
    float4* __restrict__ fn, int* __restrict__ cnt, float* __restrict__ S0rep)
{
    int t = threadIdx.x;
    if (blockIdx.x < 8) {
        int baseidx = blockIdx.x * 8192;
        #pragma unroll
        for (int it = 0; it < 32; ++it) {
            int idx = baseidx + it * 256 + t;
            float v = (idx < 32768) ? Wl[idx] : Wr[idx - 32768];
            Wbf[idx] = f2bf(v);
        }
        return;
    }

    int sb = blockIdx.x - 8;           // strip 0..255
    int base = sb * 16;
    int rep = sb & (NREP - 1);
    __shared__ int stypes[16];
    __shared__ float xs[16][HH];       // 8 KB strip stage
    int myti = -1;
    if (t < 16) {
        int row = base + t;
        int ti = sat[row]; ti = min(max(ti, 0), NTYPES - 1);
        stypes[t] = ti; myti = ti;
        const float* rp = x_now + (size_t)row * DD;
        float f0 = rp[0], f2 = rp[1], f3 = rp[2];
        float nrm = fmaxf(sqrtf(2.f * f0 * f0 + f2 * f2 + f3 * f3), 1e-12f);
        float inv = 1.f / nrm;
        fn[row] = make_float4(f0 * inv, f0 * inv, f2 * inv, f3 * inv);
    }
    #pragma unroll
    for (int it = 0; it < 8; ++it) {
        int lin = it * 256 + t;        // 0..2047
        int rl = lin >> 7, col = lin & 127;
        int row = base + rl;
        const float* rp = x_now + (size_t)row * DD;
        float v = (col == 0) ? rp[0] : rp[col - 1];
        xs[rl][col] = v;
        xbf[(size_t)row * HH + col] = f2bf(v);
    }
    __syncthreads();
    if (t < 64) {
        #pragma unroll
        for (int tt = 0; tt < NTYPES; ++tt) {
            unsigned long long m = __ballot(myti == tt);
            if (t == 0) {
                int c = __popcll(m);
                if (c) atomicAdd(&cnt[rep * NTYPES + tt], c);
            }
        }
    }
    if (t < 128) {
        float acc[NTYPES] = {0.f, 0.f, 0.f, 0.f, 0.f, 0.f};
        for (int r = 0; r < 16; ++r) {
            float v = xs[r][t];
            int tt = stypes[r];
            #pragma unroll
            for (int q = 0; q < NTYPES; ++q) acc[q] += (tt == q) ? v : 0.f;
        }
        #pragma unroll
        for (int q = 0; q < NTYPES; ++q)
            atomicAdd(&S0rep[(rep * NTYPES + q) * HH + t], acc[q]);
    }
}

// ---------------------------------------------------------------------------
// Kernel B: bitmask + degree; b-loop split across two thread-halves.
// (exact R2 version: row-major mask words)
// ---------------------------------------------------------------------------
__global__ __launch_bounds__(256) void build_mask(
    const float4* __restrict__ fn, const int* __restrict__ sat,
    const int* __restrict__ cnt, unsigned* __restrict__ mask,
    float* __restrict__ deg)
{
    int i0 = blockIdx.x * MROW;
    int t = threadIdx.x;
    int w = t & 127;
    int half = t >> 7;
    float4 fi[MROW];
    int ti[MROW];
    #pragma unroll
    for (int r = 0; r < MROW; ++r) {
        fi[r] = fn[i0 + r];
        int tt = sat[i0 + r];
        ti[r] = min(max(tt, 0), NTYPES - 1);
    }
    unsigned word[MROW] = {0, 0, 0, 0};
    int bbase = half * 16;
    for (int bb = 0; bb < 16; ++bb) {
        int b = bbase + bb;
        int j = b * 128 + w;
        float4 fj = fn[j];
        int tj = sat[j];
        #pragma unroll
        for (int r = 0; r < MROW; ++r) {
            float dot = fi[r].x * fj.x + fi[r].y * fj.y
                      + fi[r].z * fj.z + fi[r].w * fj.w;
            if (tj != ti[r] && dot > SIM_THRESH) word[r] |= (1u << b);
        }
    }
    __shared__ unsigned wpart[MROW][128];
    if (half == 1) {
        #pragma unroll
        for (int r = 0; r < MROW; ++r) wpart[r][w] = word[r];
    }
    __syncthreads();
    __shared__ int wt[2][MROW];
    if (half == 0) {
        int pcs[MROW];
        #pragma unroll
        for (int r = 0; r < MROW; ++r) {
            unsigned full = word[r] | wpart[r][w];
            mask[(size_t)(i0 + r) * 128 + w] = full;
            pcs[r] = __popc(full);
        }
        int lane = w & 63, wv2 = w >> 6;
        for (int s = 32; s; s >>= 1) {
            #pragma unroll
            for (int r = 0; r < MROW; ++r) pcs[r] += __shfl_down(pcs[r], s);
        }
        if (lane == 0) {
            #pragma unroll
            for (int r = 0; r < MROW; ++r) wt[wv2][r] = pcs[r];
        }
    }
    __syncthreads();
    if (t < MROW) {
        int r = t;
        int ctot = 0;
        #pragma unroll
        for (int rr = 0; rr < NREP; ++rr) ctot += cnt[rr * NTYPES + ti[r]];
        float d = (float)(ctot - 1 + wt[0][r] + wt[1][r]);
        deg[i0 + r] = fmaxf(d, 1.0f);
    }
}

// ---------------------------------------------------------------------------
// Kernel W (R9, NEW): per-XCD L2 warm. The gather's scattered 128B reads are
// cold every iteration (harness poison fill evicts L2/L3; and gather-2's
// operand h1bf is dirty in the PRODUCER block's XCD L2 — per-XCD L2s are not
// cross-coherent, so remote readers miss). This kernel streams the operand
// tables coalesced: 256 blocks, block reads stripe (bid&7) of each table, so
// each XCD's ~32 resident blocks (any sane bid->XCD mapping includes all 8
// residues) collectively pull the WHOLE table into their own L2 at full
// BW/MLP. The following gather then hits local L2 (~its warm floor).
// asm consume prevents DCE (rule #17).
// ---------------------------------------------------------------------------
__global__ __launch_bounds__(256) void warm(
    const uint4* __restrict__ a, int n4a,
    const uint4* __restrict__ b, int n4b)
{
    int s = blockIdx.x & 7;
    unsigned acc = 0;
    int pa = n4a >> 3;
    for (int i = s * pa + threadIdx.x; i < (s + 1) * pa; i += 256) {
        uint4 v = a[i];
        acc ^= v.x ^ v.y ^ v.z ^ v.w;
    }
    if (n4b > 0) {
        int pb = n4b >> 3;
        for (int i = s * pb + threadIdx.x; i < (s + 1) * pb; i += 256) {
            uint4 v = b[i];
            acc ^= v.x ^ v.y ^ v.z ^ v.w;
        }
    }
    asm volatile("" :: "v"(acc));
}

// ---------------------------------------------------------------------------
// Kernel G (gather, R2/R3 structure): two waves per row, bf16 gather with
// packed f32 accumulate; self term from bf16 array.
// ---------------------------------------------------------------------------
__global__ __launch_bounds__(256, 8) void gather_kernel(
    const ushortT* __restrict__ hbf, const unsigned* __restrict__ mask,
    const float* __restrict__ deg, const float* __restrict__ S,
    const int* __restrict__ sat, ushortT* __restrict__ mbf)
{
    int t = threadIdx.x;
    int wv = t >> 6;          // wave id 0..3
    int lane = t & 63;
    int r  = wv >> 1;         // row slot 0..1
    int hf = wv & 1;          // half 0..1
    int i0 = blockIdx.x * 2;
    int i = i0 + r;

    __shared__ ushortT list[4][LMAXH];                   // 2 KB
    __shared__ __align__(16) float part[4][HH];          // 2 KB
    __shared__ int tarr[2];

    if (t < 2) {
        int tt = sat[i0 + t];
        tarr[t] = min(max(tt, 0), NTYPES - 1);
    }

    // ---- decode: wave (r,hf) owns mask words hf*64+lane of row i ----
    int widx = hf * 64 + lane;
    unsigned word = mask[(size_t)i * 128 + widx];
    int pc = __popc(word);
    int x = pc;
    for (int s = 1; s < 64; s <<= 1) {
        int v = __shfl_up(x, s);
        if (lane >= s) x += v;
    }
    int ncnt = __shfl(x, 63);
    int ofs = x - pc;
    unsigned ww = word;
    while (ww) {
        int b = __ffs(ww) - 1; ww &= ww - 1;
        list[wv][ofs++] = (ushortT)(b * 128 + widx);
    }

    // ---- gather own half-list from bf16 rows: 4 rows/instr, 6 deep ----
    int q = lane >> 4;        // 0..3 neighbor slot
    int c = lane & 15;        // 0..15 -> columns 8c..8c+7
    const uint4* __restrict__ hb4 = (const uint4*)hbf;
    f32x2 acc2[4] = {{0.f, 0.f}, {0.f, 0.f}, {0.f, 0.f}, {0.f, 0.f}};
    int g = 0;
    for (; g + 24 <= ncnt; g += 24) {
        int j0 = list[wv][g + q];
        int j1 = list[wv][g + 4 + q];
        int j2 = list[wv][g + 8 + q];
        int j3 = list[wv][g + 12 + q];
        int j4 = list[wv][g + 16 + q];
        int j5 = list[wv][g + 20 + q];
        uint4 v0 = hb4[j0 * 16 + c];
        uint4 v1 = hb4[j1 * 16 + c];
        uint4 v2 = hb4[j2 * 16 + c];
        uint4 v3 = hb4[j3 * 16 + c];
        uint4 v4 = hb4[j4 * 16 + c];
        uint4 v5 = hb4[j5 * 16 + c];
        BFACC(v0); BFACC(v1); BFACC(v2); BFACC(v3); BFACC(v4); BFACC(v5);
    }
    for (; g + 4 <= ncnt; g += 4) {
        int j0 = list[wv][g + q];
        uint4 v0 = hb4[j0 * 16 + c];
        BFACC(v0);
    }
    if (q < ncnt - g) {
        int j0 = list[wv][g + q];
        uint4 v0 = hb4[j0 * 16 + c];
        BFACC(v0);
    }
    #pragma unroll
    for (int d = 0; d < 4; ++d) {
        acc2[d].x += __shfl_down(acc2[d].x, 32);
        acc2[d].y += __shfl_down(acc2[d].y, 32);
        acc2[d].x += __shfl_down(acc2[d].x, 16);
        acc2[d].y += __shfl_down(acc2[d].y, 16);
    }
    if (lane < 16) {
        float4 p0 = {acc2[0].x, acc2[0].y, acc2[1].x, acc2[1].y};
        float4 p1 = {acc2[2].x, acc2[2].y, acc2[3].x, acc2[3].y};
        ((float4*)part[wv])[c * 2] = p0;
        ((float4*)part[wv])[c * 2 + 1] = p1;
    }
    __syncthreads();   // partials + tarr ready

    if (hf == 0 && lane < 32) {
        int cc = lane;
        float4 p0 = ((const float4*)part[wv])[cc];
        float4 p1 = ((const float4*)part[wv + 1])[cc];
        int ti = tarr[r];
        float rdeg = 1.f / deg[i];
        uint2 hw = ((const uint2*)(hbf + (size_t)i * HH))[cc];
        float4 hv = {bflo(hw.x), bfhi(hw.x), bflo(hw.y), bfhi(hw.y)};
        float4 Sv = {0.f, 0.f, 0.f, 0.f};
        #pragma unroll
        for (int rr = 0; rr < NREP; ++rr) {
            float4 sv = ((const float4*)S)[(rr * NTYPES + ti) * 32 + cc];
            Sv.x += sv.x; Sv.y += sv.y; Sv.z += sv.z; Sv.w += sv.w;
        }
        float4 m;
        m.x = (Sv.x - hv.x + p0.x + p1.x) * rdeg;
        m.y = (Sv.y - hv.y + p0.y + p1.y) * rdeg;
        m.z = (Sv.z - hv.z + p0.z + p1.z) * rdeg;
        m.w = (Sv.w - hv.w + p0.w + p1.w) * rdeg;
        ushort4 mb;
        mb.x = f2bf(m.x); mb.y = f2bf(m.y);
        mb.z = f2bf(m.z); mb.w = f2bf(m.w);
        ((ushort4*)(mbf + (size_t)i * HH))[cc] = mb;
    }
}

// ---------------------------------------------------------------------------
// Kernel M1 (layer-1 MFMA GEMM, 512 threads / 8 waves).
// ---------------------------------------------------------------------------
__global__ __launch_bounds__(512) void gemm_l1(
    const ushortT* __restrict__ mbf, const ushortT* __restrict__ hbf,
    const ushortT* __restrict__ Wlbf, const ushortT* __restrict__ Wrbf,
    const float* __restrict__ bl, const int* __restrict__ sat,
    ushortT* __restrict__ houtbf, float* __restrict__ acc0)
{
    int t = threadIdx.x;
    int wv = t >> 6, lane = t & 63;
    int p = lane & 15, q = lane >> 4;
    int i0 = blockIdx.x * 16;

    __shared__ float sh[16][129];
    __shared__ int stypes[16];
    if (t < 16) {
        int tt = sat[i0 + t];
        stypes[t] = min(max(tt, 0), NTYPES - 1);
    }

    const ushortT* arow_m = mbf + (size_t)(i0 + p) * HH + q * 8;
    const ushortT* arow_h = hbf + (size_t)(i0 + p) * HH + q * 8;
    short8 am[4], ah[4];
    #pragma unroll
    for (int s = 0; s < 4; ++s) {
        am[s] = *(const short8*)(arow_m + s * 32);
        ah[s] = *(const short8*)(arow_h + s * 32);
    }

    int n0 = wv * 16;                 // one n-tile per wave
    const ushortT* brow_l = Wlbf + (size_t)(n0 + p) * HH + q * 8;
    const ushortT* brow_r = Wrbf + (size_t)(n0 + p) * HH + q * 8;
    f32x4 acc = {0.f, 0.f, 0.f, 0.f};
    #pragma unroll
    for (int s = 0; s < 4; ++s) {
        short8 b = *(const short8*)(brow_l + s * 32);
        acc = __builtin_amdgcn_mfma_f32_16x16x32_bf16(am[s], b, acc, 0, 0, 0);
    }
    #pragma unroll
    for (int s = 0; s < 4; ++s) {
        short8 b = *(const short8*)(brow_r + s * 32);
        acc = __builtin_amdgcn_mfma_f32_16x16x32_bf16(ah[s], b, acc, 0, 0, 0);
    }
    int o = n0 + p;                   // D col = lane&15
    float bv = bl[o];
    #pragma unroll
    for (int rg = 0; rg < 4; ++rg) {
        float v = fmaxf(acc[rg] + bv, 0.f);
        sh[q * 4 + rg][o] = v;        // D row = quad*4 + reg
    }
    __syncthreads();

    #pragma unroll
    for (int e = 0; e < 4; ++e) {
        int lin = e * 512 + t;
        int rr = lin >> 7, cc = lin & 127;
        houtbf[(size_t)i0 * HH + lin] = f2bf(sh[rr][cc]);
    }
    int rep = blockIdx.x & (NREP - 1);
    if (t < HH) {
        float accq[NTYPES] = {0.f, 0.f, 0.f, 0.f, 0.f, 0.f};
        for (int r = 0; r < 16; ++r) {
            float v = sh[r][t];
            int tt = stypes[r];
            #pragma unroll
            for (int qq = 0; qq < NTYPES; ++qq)
                accq[qq] += (tt == qq) ? v : 0.f;
        }
        #pragma unroll
        for (int qq = 0; qq < NTYPES; ++qq)
            atomicAdd(&acc0[(rep * NTYPES + qq) * HH + t], accq[qq]);
    }
}

// ---------------------------------------------------------------------------
// Kernel M2 (layer-2 MFMA GEMM, 512 threads / 8 waves): fp32 h2 + BN stats.
// ---------------------------------------------------------------------------
__global__ __launch_bounds__(512) void gemm_l2(
    const ushortT* __restrict__ mbf, const ushortT* __restrict__ hbf,
    const ushortT* __restrict__ Wlbf, const ushortT* __restrict__ Wrbf,
    const float* __restrict__ bl, float* __restrict__ hout,
    float* __restrict__ acc0, float* __restrict__ acc1)
{
    int t = threadIdx.x;
    int wv = t >> 6, lane = t & 63;
    int p = lane & 15, q = lane >> 4;
    int i0 = blockIdx.x * 16;

    __shared__ float sh[16][129];

    const ushortT* arow_m = mbf + (size_t)(i0 + p) * HH + q * 8;
    const ushortT* arow_h = hbf + (size_t)(i0 + p) * HH + q * 8;
    short8 am[4], ah[4];
    #pragma unroll
    for (int s = 0; s < 4; ++s) {
        am[s] = *(const short8*)(arow_m + s * 32);
        ah[s] = *(const short8*)(arow_h + s * 32);
    }

    int n0 = wv * 16;
    const ushortT* brow_l = Wlbf + (size_t)(n0 + p) * HH + q * 8;
    const ushortT* brow_r = Wrbf + (size_t)(n0 + p) * HH + q * 8;
    f32x4 acc = {0.f, 0.f, 0.f, 0.f};
    #pragma unroll
    for (int s = 0; s < 4; ++s) {
        short8 b = *(const short8*)(brow_l + s * 32);
        acc = __builtin_amdgcn_mfma_f32_16x16x32_bf16(am[s], b, acc, 0, 0, 0);
    }
    #pragma unroll
    for (int s = 0; s < 4; ++s) {
        short8 b = *(const short8*)(brow_r + s * 32);
        acc = __builtin_amdgcn_mfma_f32_16x16x32_bf16(ah[s], b, acc, 0, 0, 0);
    }
    int o = n0 + p;
    float bv = bl[o];
    #pragma unroll
    for (int rg = 0; rg < 4; ++rg) {
        float v = fmaxf(acc[rg] + bv, 0.f);
        sh[q * 4 + rg][o] = v;
    }
    __syncthreads();

    #pragma unroll
    for (int e = 0; e < 4; ++e) {
        int lin = e * 512 + t;
        int rr = lin >> 7, cc = lin & 127;
        hout[(size_t)i0 * HH + lin] = sh[rr][cc];
    }
    int rep = blockIdx.x & (NREP - 1);
    if (t < HH) {
        float s = 0.f, s2 = 0.f;
        for (int r = 0; r < 16; ++r) {
            float v = sh[r][t];
            s += v; s2 += v * v;
        }
        atomicAdd(&acc0[rep * HH + t], s);
        atomicAdd(&acc1[rep * HH + t], s2);
    }
}

// ---------------------------------------------------------------------------
// Kernel F: BN apply + head, one wave per row; sums the NREP stat replicas.
// ---------------------------------------------------------------------------
__global__ __launch_bounds__(256) void finalize(
    const float* __restrict__ h, const float* __restrict__ musum8,
    const float* __restrict__ varsum8, const float* __restrict__ gamma,
    const float* __restrict__ beta, const float* __restrict__ Wo,
    const float* __restrict__ bo, float* __restrict__ out_h,
    float* __restrict__ out_o)
{
    int t = threadIdx.x;
    int wv = t >> 6;
    int lane = t & 63;
    int i = blockIdx.x * 4 + wv;

    float2 mus = {0.f, 0.f}, vas = {0.f, 0.f};
    #pragma unroll
    for (int r = 0; r < NREP; ++r) {
        float2 a = ((const float2*)(musum8 + r * HH))[lane];
        float2 b = ((const float2*)(varsum8 + r * HH))[lane];
        mus.x += a.x; mus.y += a.y;
        vas.x += b.x; vas.y += b.y;
    }
    float2 ga  = ((const float2*)gamma)[lane];
    float2 be  = ((const float2*)beta)[lane];
    float mu0 = mus.x * (1.f / NN), mu1 = mus.y * (1.f / NN);
    float v0 = vas.x * (1.f / NN) - mu0 * mu0;
    float v1 = vas.y * (1.f / NN) - mu1 * mu1;
    float sc0 = ga.x / sqrtf(v0 + BN_EPS), sc1 = ga.y / sqrtf(v1 + BN_EPS);
    float sh0 = be.x - mu0 * sc0, sh1 = be.y - mu1 * sc1;

    float2 hv = ((const float2*)(h + (size_t)i * HH))[lane];
    float2 hb;
    hb.x = hv.x * sc0 + sh0;
    hb.y = hv.y * sc1 + sh1;
    ((float2*)(out_h + (size_t)i * HH))[lane] = hb;

    float2 w0 = ((const float2*)Wo)[lane];
    float2 w1 = ((const float2*)(Wo + HH))[lane];
    float2 w2 = ((const float2*)(Wo + 2 * HH))[lane];
    float p0 = hb.x * w0.x + hb.y * w0.y;
    float p1 = hb.x * w1.x + hb.y * w1.y;
    float p2 = hb.x * w2.x + hb.y * w2.y;
    for (int s = 32; s; s >>= 1) {
        p0 += __shfl_down(p0, s);
        p1 += __shfl_down(p1, s);
        p2 += __shfl_down(p2, s);
    }
    if (lane == 0) {
        out_o[(size_t)i * OUTD + 0] = p0 + bo[0];
        out_o[(size_t)i * OUTD + 1] = p1 + bo[1];
        out_o[(size_t)i * OUTD + 2] = p2 + bo[2];
    }
}

// ---------------------------------------------------------------------------
extern "C" void kernel_launch(void* const* d_in, const int* in_sizes, int n_in,
                              void* d_out, int out_size, void* d_ws, size_t ws_size,
                              hipStream_t stream)
{
    (void)in_sizes; (void)n_in; (void)out_size; (void)ws_size;
    const float* x_now = (const float*)d_in[0];
    const int*   sat   = (const int*)d_in[1];
    const float* Wl    = (const float*)d_in[2];
    const float* bl    = (const float*)d_in[3];
    const float* Wr    = (const float*)d_in[4];
    const float* gamma = (const float*)d_in[5];
    const float* beta  = (const float*)d_in[6];
    const float* Wo    = (const float*)d_in[7];
    const float* bo    = (const float*)d_in[8];

    ushortT* Wbf  = (ushortT*)d_ws;               // 65536 us [Wl0,Wl1,Wr0,Wr1]
    ushortT* x0bf = Wbf + 65536;                  // 524288 us
    ushortT* h1bf = x0bf + (size_t)NN * HH;       // 524288 us
    ushortT* mbf  = h1bf + (size_t)NN * HH;       // 524288 us (both layers)
    float* h2 = (float*)(mbf + (size_t)NN * HH);  // 524288 f
    float4* fn = (float4*)(h2 + (size_t)NN * HH);       // 4096 float4
    unsigned* mask = (unsigned*)((float*)fn + 4 * NN);  // 524288 words
    float* deg = (float*)(mask + (size_t)NN * 128);     // 4096
    // ---- zeroed accumulator region (one contiguous memset) ----
    int*   cnt   = (int*)(deg + NN);              // NREP*6 (reserve 64)
    float* S0rep = (float*)(cnt + 64);            // 6144
    float* S1rep = S0rep + NREP * NTYPES * HH;    // 6144
    float* mu8   = S1rep + NREP * NTYPES * HH;    // 1024
    float* var8  = mu8 + NREP * HH;               // 1024

    size_t zero_bytes = (64 + 2 * NREP * NTYPES * HH + 2 * NREP * HH)
                        * sizeof(float);
    hipMemsetAsync(cnt, 0, zero_bytes, stream);

    prep<<<264, 256, 0, stream>>>(x_now, sat, Wl, Wr, Wbf, x0bf, fn, cnt,
                                  S0rep);
    build_mask<<<NN / MROW, 256, 0, stream>>>(fn, sat, cnt, mask, deg);

    // layer 1: warm x0bf (1 MB) + mask (2 MB) into every XCD's L2, then gather
    warm<<<256, 256, 0, stream>>>((const uint4*)x0bf, NN * HH / 8,
                                  (const uint4*)mask, NN * 128 / 4);
    gather_kernel<<<NN / 2, 256, 0, stream>>>(x0bf, mask, deg, S0rep, sat,
                                              mbf);
    gemm_l1<<<NN / 16, 512, 0, stream>>>(mbf, x0bf, Wbf, Wbf + 32768, bl, sat,
                                         h1bf, S1rep);

    // layer 2: warm h1bf (written on producer XCDs only) then gather
    warm<<<256, 256, 0, stream>>>((const uint4*)h1bf, NN * HH / 8,
                                  (const uint4*)nullptr, 0);
    gather_kernel<<<NN / 2, 256, 0, stream>>>(h1bf, mask, deg, S1rep, sat,
                                              mbf);
    gemm_l2<<<NN / 16, 512, 0, stream>>>(mbf, h1bf, Wbf + 16384, Wbf + 49152,
                                         bl + HH, h2, mu8, var8);

    finalize<<<NN / 4, 256, 0, stream>>>(h2, mu8, var8, gamma, beta, Wo, bo,
                                         (float*)d_out, (float*)d_out + (size_t)NN * HH);
}

// Round 10
// 133.052 us; speedup vs baseline: 1.3478x; 1.1722x over previous
//
#include <hip/hip_runtime.h>
#include <math.h>

#define NN 4096
#define DD 127
#define HH 128
#define OUTD 3
#define NTYPES 6
#define SIM_THRESH 0.9f
#define BN_EPS 1e-5f
#define MROW 4    // rows per block in build_mask
#define NREP 8    // accumulator replicas
// Half-row neighbor list capacity. Half-degree ~ Binomial(1706, 0.05):
// mean 85, sigma 9 -> 256 = 19-sigma bound.
#define LMAXH 256

typedef unsigned short ushortT;
typedef __attribute__((ext_vector_type(8))) short short8;   // 8 bf16 (4 VGPRs)
typedef __attribute__((ext_vector_type(4))) float f32x4;

// round-to-nearest-even fp32 -> bf16 (bit pattern)
static __device__ inline ushortT f2bf(float f) {
    unsigned u = __float_as_uint(f);
    unsigned r = (u + 0x7fffu + ((u >> 16) & 1u)) >> 16;
    return (ushortT)r;
}
static __device__ inline float bflo(unsigned w) { return __uint_as_float(w << 16); }
static __device__ inline float bfhi(unsigned w) { return __uint_as_float(w & 0xffff0000u); }

#define BFACC(vv)                                                         \
    {                                                                     \
        acc[0] += __uint_as_float((vv).x << 16);                          \
        acc[1] += __uint_as_float((vv).x & 0xffff0000u);                  \
        acc[2] += __uint_as_float((vv).y << 16);                          \
        acc[3] += __uint_as_float((vv).y & 0xffff0000u);                  \
        acc[4] += __uint_as_float((vv).z << 16);                          \
        acc[5] += __uint_as_float((vv).z & 0xffff0000u);                  \
        acc[6] += __uint_as_float((vv).w << 16);                          \
        acc[7] += __uint_as_float((vv).w & 0xffff0000u);                  \
    }

// ---------------------------------------------------------------------------
// Kernel P: blocks 0..7 convert W (Wl0,Wl1,Wr0,Wr1) to bf16 row-major.
// Blocks 8..263: 16-row strips: xbf (bf16 only — fp32 x dropped; strip staged
// in LDS for the S0 sums), fn, type histogram, S0 type-sums (NREP replicas).
// ---------------------------------------------------------------------------
__global__ __launch_bounds__(256) void prep(
    const float* __restrict__ x_now, const int* __restrict__ sat,
    const float* __restrict__ Wl, const float* __restrict__ Wr,
    ushortT* __restrict__ Wbf, ushortT* __restrict__ xbf,
    float4* __restrict__ fn, int* __restrict__ cnt, float* __restrict__ S0rep)
{
    int t = threadIdx.x;
    if (blockIdx.x < 8) {
        int baseidx = blockIdx.x * 8192;
        #pragma unroll
        for (int it = 0; it < 32; ++it) {
            int idx = baseidx + it * 256 + t;
            float v = (idx < 32768) ? Wl[idx] : Wr[idx - 32768];
            Wbf[idx] = f2bf(v);
        }
        return;
    }

    int sb = blockIdx.x - 8;           // strip 0..255
    int base = sb * 16;
    int rep = sb & (NREP - 1);
    __shared__ int stypes[16];
    __shared__ float xs[16][HH];       // 8 KB strip stage
    int myti = -1;
    if (t < 16) {
        int row = base + t;
        int ti = sat[row]; ti = min(max(ti, 0), NTYPES - 1);
        stypes[t] = ti; myti = ti;
        const float* rp = x_now + (size_t)row * DD;
        float f0 = rp[0], f2 = rp[1], f3 = rp[2];
        float nrm = fmaxf(sqrtf(2.f * f0 * f0 + f2 * f2 + f3 * f3), 1e-12f);
        float inv = 1.f / nrm;
        fn[row] = make_float4(f0 * inv, f0 * inv, f2 * inv, f3 * inv);
    }
    #pragma unroll
    for (int it = 0; it < 8; ++it) {
        int lin = it * 256 + t;        // 0..2047
        int rl = lin >> 7, col = lin & 127;
        int row = base + rl;
        const float* rp = x_now + (size_t)row * DD;
        float v = (col == 0) ? rp[0] : rp[col - 1];
        xs[rl][col] = v;
        xbf[(size_t)row * HH + col] = f2bf(v);
    }
    __syncthreads();
    if (t < 64) {
        #pragma unroll
        for (int tt = 0; tt < NTYPES; ++tt) {
            unsigned long long m = __ballot(myti == tt);
            if (t == 0) {
                int c = __popcll(m);
                if (c) atomicAdd(&cnt[rep * NTYPES + tt], c);
            }
        }
    }
    if (t < 128) {
        float acc[NTYPES] = {0.f, 0.f, 0.f, 0.f, 0.f, 0.f};
        for (int r = 0; r < 16; ++r) {
            float v = xs[r][t];
            int tt = stypes[r];
            #pragma unroll
            for (int q = 0; q < NTYPES; ++q) acc[q] += (tt == q) ? v : 0.f;
        }
        #pragma unroll
        for (int q = 0; q < NTYPES; ++q)
            atomicAdd(&S0rep[(rep * NTYPES + q) * HH + t], acc[q]);
    }
}

// ---------------------------------------------------------------------------
// Kernel B: bitmask + degree; b-loop split across two thread-halves.
// ---------------------------------------------------------------------------
__global__ __launch_bounds__(256) void build_mask(
    const float4* __restrict__ fn, const int* __restrict__ sat,
    const int* __restrict__ cnt, unsigned* __restrict__ mask,
    float* __restrict__ deg)
{
    int i0 = blockIdx.x * MROW;
    int t = threadIdx.x;
    int w = t & 127;
    int half = t >> 7;
    float4 fi[MROW];
    int ti[MROW];
    #pragma unroll
    for (int r = 0; r < MROW; ++r) {
        fi[r] = fn[i0 + r];
        int tt = sat[i0 + r];
        ti[r] = min(max(tt, 0), NTYPES - 1);
    }
    unsigned word[MROW] = {0, 0, 0, 0};
    int bbase = half * 16;
    for (int bb = 0; bb < 16; ++bb) {
        int b = bbase + bb;
        int j = b * 128 + w;
        float4 fj = fn[j];
        int tj = sat[j];
        #pragma unroll
        for (int r = 0; r < MROW; ++r) {
            float dot = fi[r].x * fj.x + fi[r].y * fj.y
                      + fi[r].z * fj.z + fi[r].w * fj.w;
            if (tj != ti[r] && dot > SIM_THRESH) word[r] |= (1u << b);
        }
    }
    __shared__ unsigned wpart[MROW][128];
    if (half == 1) {
        #pragma unroll
        for (int r = 0; r < MROW; ++r) wpart[r][w] = word[r];
    }
    __syncthreads();
    __shared__ int wt[2][MROW];
    if (half == 0) {
        int pcs[MROW];
        #pragma unroll
        for (int r = 0; r < MROW; ++r) {
            unsigned full = word[r] | wpart[r][w];
            mask[(size_t)(i0 + r) * 128 + w] = full;
            pcs[r] = __popc(full);
        }
        int lane = w & 63, wv2 = w >> 6;
        for (int s = 32; s; s >>= 1) {
            #pragma unroll
            for (int r = 0; r < MROW; ++r) pcs[r] += __shfl_down(pcs[r], s);
        }
        if (lane == 0) {
            #pragma unroll
            for (int r = 0; r < MROW; ++r) wt[wv2][r] = pcs[r];
        }
    }
    __syncthreads();
    if (t < MROW) {
        int r = t;
        int ctot = 0;
        #pragma unroll
        for (int rr = 0; rr < NREP; ++rr) ctot += cnt[rr * NTYPES + ti[r]];
        float d = (float)(ctot - 1 + wt[0][r] + wt[1][r]);
        deg[i0 + r] = fmaxf(d, 1.0f);
    }
}

// ---------------------------------------------------------------------------
// Kernel G (gather-only): two waves per row, bf16 gather; writes m as bf16.
// Self term read directly from the bf16 array in the epilogue.
// ---------------------------------------------------------------------------
__global__ __launch_bounds__(256, 8) void gather_kernel(
    const ushortT* __restrict__ hbf, const unsigned* __restrict__ mask,
    const float* __restrict__ deg, const float* __restrict__ S,
    const int* __restrict__ sat, ushortT* __restrict__ mbf)
{
    int t = threadIdx.x;
    int wv = t >> 6;          // wave id 0..3
    int lane = t & 63;
    int r  = wv >> 1;         // row slot 0..1
    int hf = wv & 1;          // half 0..1
    int i0 = blockIdx.x * 2;
    int i = i0 + r;

    __shared__ ushortT list[4][LMAXH];                   // 2 KB
    __shared__ __align__(16) float part[4][HH];          // 2 KB
    __shared__ int tarr[2];

    if (t < 2) {
        int tt = sat[i0 + t];
        tarr[t] = min(max(tt, 0), NTYPES - 1);
    }

    // ---- decode: wave (r,hf) owns mask words hf*64+lane of row i ----
    int widx = hf * 64 + lane;
    unsigned word = mask[(size_t)i * 128 + widx];
    int pc = __popc(word);
    int x = pc;
    for (int s = 1; s < 64; s <<= 1) {
        int v = __shfl_up(x, s);
        if (lane >= s) x += v;
    }
    int ncnt = __shfl(x, 63);
    int ofs = x - pc;
    unsigned ww = word;
    while (ww) {
        int b = __ffs(ww) - 1; ww &= ww - 1;
        list[wv][ofs++] = (ushortT)(b * 128 + widx);
    }

    // ---- gather own half-list from bf16 rows: 4 rows/instr, 6 deep ----
    int q = lane >> 4;        // 0..3 neighbor slot
    int c = lane & 15;        // 0..15 -> columns 8c..8c+7
    const uint4* __restrict__ hb4 = (const uint4*)hbf;
    float acc[8] = {0.f, 0.f, 0.f, 0.f, 0.f, 0.f, 0.f, 0.f};
    int g = 0;
    for (; g + 24 <= ncnt; g += 24) {
        int j0 = list[wv][g + q];
        int j1 = list[wv][g + 4 + q];
        int j2 = list[wv][g + 8 + q];
        int j3 = list[wv][g + 12 + q];
        int j4 = list[wv][g + 16 + q];
        int j5 = list[wv][g + 20 + q];
        uint4 v0 = hb4[j0 * 16 + c];
        uint4 v1 = hb4[j1 * 16 + c];
        uint4 v2 = hb4[j2 * 16 + c];
        uint4 v3 = hb4[j3 * 16 + c];
        uint4 v4 = hb4[j4 * 16 + c];
        uint4 v5 = hb4[j5 * 16 + c];
        BFACC(v0); BFACC(v1); BFACC(v2); BFACC(v3); BFACC(v4); BFACC(v5);
    }
    for (; g + 4 <= ncnt; g += 4) {
        int j0 = list[wv][g + q];
        uint4 v0 = hb4[j0 * 16 + c];
        BFACC(v0);
    }
    if (q < ncnt - g) {
        int j0 = list[wv][g + q];
        uint4 v0 = hb4[j0 * 16 + c];
        BFACC(v0);
    }
    #pragma unroll
    for (int d = 0; d < 8; ++d) {
        acc[d] += __shfl_down(acc[d], 32);
        acc[d] += __shfl_down(acc[d], 16);
    }
    if (lane < 16) {
        float4 p0 = {acc[0], acc[1], acc[2], acc[3]};
        float4 p1 = {acc[4], acc[5], acc[6], acc[7]};
        ((float4*)part[wv])[c * 2] = p0;
        ((float4*)part[wv])[c * 2 + 1] = p1;
    }
    __syncthreads();   // partials + tarr ready

    if (hf == 0 && lane < 32) {
        int cc = lane;
        float4 p0 = ((const float4*)part[wv])[cc];
        float4 p1 = ((const float4*)part[wv + 1])[cc];
        int ti = tarr[r];
        float rdeg = 1.f / deg[i];
        uint2 hw = ((const uint2*)(hbf + (size_t)i * HH))[cc];
        float4 hv = {bflo(hw.x), bfhi(hw.x), bflo(hw.y), bfhi(hw.y)};
        float4 Sv = {0.f, 0.f, 0.f, 0.f};
        #pragma unroll
        for (int rr = 0; rr < NREP; ++rr) {
            float4 sv = ((const float4*)S)[(rr * NTYPES + ti) * 32 + cc];
            Sv.x += sv.x; Sv.y += sv.y; Sv.z += sv.z; Sv.w += sv.w;
        }
        float4 m;
        m.x = (Sv.x - hv.x + p0.x + p1.x) * rdeg;
        m.y = (Sv.y - hv.y + p0.y + p1.y) * rdeg;
        m.z = (Sv.z - hv.z + p0.z + p1.z) * rdeg;
        m.w = (Sv.w - hv.w + p0.w + p1.w) * rdeg;
        ushort4 mb;
        mb.x = f2bf(m.x); mb.y = f2bf(m.y);
        mb.z = f2bf(m.z); mb.w = f2bf(m.w);
        ((ushort4*)(mbf + (size_t)i * HH))[cc] = mb;
    }
}

// ---------------------------------------------------------------------------
// Kernel M1 (layer-1 MFMA GEMM): h1 = relu([mbf | xbf] @ [Wl0 | Wr0]^T + bl0).
// Writes bf16 h1 only + next-layer type sums.
// ---------------------------------------------------------------------------
__global__ __launch_bounds__(256) void gemm_l1(
    const ushortT* __restrict__ mbf, const ushortT* __restrict__ hbf,
    const ushortT* __restrict__ Wlbf, const ushortT* __restrict__ Wrbf,
    const float* __restrict__ bl, const int* __restrict__ sat,
    ushortT* __restrict__ houtbf, float* __restrict__ acc0)
{
    int t = threadIdx.x;
    int wv = t >> 6, lane = t & 63;
    int p = lane & 15, q = lane >> 4;
    int i0 = blockIdx.x * 16;

    __shared__ float sh[16][129];
    __shared__ int stypes[16];
    if (t < 16) {
        int tt = sat[i0 + t];
        stypes[t] = min(max(tt, 0), NTYPES - 1);
    }

    // A fragments: row i0+p, k = s*32 + q*8 .. +7 (k-contiguous per lane)
    const ushortT* arow_m = mbf + (size_t)(i0 + p) * HH + q * 8;
    const ushortT* arow_h = hbf + (size_t)(i0 + p) * HH + q * 8;
    short8 am[4], ah[4];
    #pragma unroll
    for (int s = 0; s < 4; ++s) {
        am[s] = *(const short8*)(arow_m + s * 32);
        ah[s] = *(const short8*)(arow_h + s * 32);
    }

    #pragma unroll
    for (int nt = 0; nt < 2; ++nt) {
        int n0 = (wv * 2 + nt) * 16;
        const ushortT* brow_l = Wlbf + (size_t)(n0 + p) * HH + q * 8;
        const ushortT* brow_r = Wrbf + (size_t)(n0 + p) * HH + q * 8;
        f32x4 acc = {0.f, 0.f, 0.f, 0.f};
        #pragma unroll
        for (int s = 0; s < 4; ++s) {
            short8 b = *(const short8*)(brow_l + s * 32);
            acc = __builtin_amdgcn_mfma_f32_16x16x32_bf16(am[s], b, acc, 0, 0, 0);
        }
        #pragma unroll
        for (int s = 0; s < 4; ++s) {
            short8 b = *(const short8*)(brow_r + s * 32);
            acc = __builtin_amdgcn_mfma_f32_16x16x32_bf16(ah[s], b, acc, 0, 0, 0);
        }
        int o = n0 + p;              // D col = lane&15
        float bv = bl[o];
        #pragma unroll
        for (int rg = 0; rg < 4; ++rg) {
            float v = fmaxf(acc[rg] + bv, 0.f);
            sh[q * 4 + rg][o] = v;   // D row = quad*4 + reg
        }
    }
    __syncthreads();

    #pragma unroll
    for (int e = 0; e < 8; ++e) {
        int lin = e * 256 + t;
        int rr = lin >> 7, cc = lin & 127;
        houtbf[(size_t)i0 * HH + lin] = f2bf(sh[rr][cc]);
    }
    int rep = blockIdx.x & (NREP - 1);
    if (t < HH) {
        float accq[NTYPES] = {0.f, 0.f, 0.f, 0.f, 0.f, 0.f};
        for (int r = 0; r < 16; ++r) {
            float v = sh[r][t];
            int tt = stypes[r];
            #pragma unroll
            for (int qq = 0; qq < NTYPES; ++qq)
                accq[qq] += (tt == qq) ? v : 0.f;
        }
        #pragma unroll
        for (int qq = 0; qq < NTYPES; ++qq)
            atomicAdd(&acc0[(rep * NTYPES + qq) * HH + t], accq[qq]);
    }
}

// ---------------------------------------------------------------------------
// Kernel M2 (layer-2 MFMA GEMM): writes fp32 h2 + BN stat replicas.
// ---------------------------------------------------------------------------
__global__ __launch_bounds__(256) void gemm_l2(
    const ushortT* __restrict__ mbf, const ushortT* __restrict__ hbf,
    const ushortT* __restrict__ Wlbf, const ushortT* __restrict__ Wrbf,
    const float* __restrict__ bl, float* __restrict__ hout,
    float* __restrict__ acc0, float* __restrict__ acc1)
{
    int t = threadIdx.x;
    int wv = t >> 6, lane = t & 63;
    int p = lane & 15, q = lane >> 4;
    int i0 = blockIdx.x * 16;

    __shared__ float sh[16][129];

    const ushortT* arow_m = mbf + (size_t)(i0 + p) * HH + q * 8;
    const ushortT* arow_h = hbf + (size_t)(i0 + p) * HH + q * 8;
    short8 am[4], ah[4];
    #pragma unroll
    for (int s = 0; s < 4; ++s) {
        am[s] = *(const short8*)(arow_m + s * 32);
        ah[s] = *(const short8*)(arow_h + s * 32);
    }

    #pragma unroll
    for (int nt = 0; nt < 2; ++nt) {
        int n0 = (wv * 2 + nt) * 16;
        const ushortT* brow_l = Wlbf + (size_t)(n0 + p) * HH + q * 8;
        const ushortT* brow_r = Wrbf + (size_t)(n0 + p) * HH + q * 8;
        f32x4 acc = {0.f, 0.f, 0.f, 0.f};
        #pragma unroll
        for (int s = 0; s < 4; ++s) {
            short8 b = *(const short8*)(brow_l + s * 32);
            acc = __builtin_amdgcn_mfma_f32_16x16x32_bf16(am[s], b, acc, 0, 0, 0);
        }
        #pragma unroll
        for (int s = 0; s < 4; ++s) {
            short8 b = *(const short8*)(brow_r + s * 32);
            acc = __builtin_amdgcn_mfma_f32_16x16x32_bf16(ah[s], b, acc, 0, 0, 0);
        }
        int o = n0 + p;
        float bv = bl[o];
        #pragma unroll
        for (int rg = 0; rg < 4; ++rg) {
            float v = fmaxf(acc[rg] + bv, 0.f);
            sh[q * 4 + rg][o] = v;
        }
    }
    __syncthreads();

    #pragma unroll
    for (int e = 0; e < 8; ++e) {
        int lin = e * 256 + t;
        int rr = lin >> 7, cc = lin & 127;
        hout[(size_t)i0 * HH + lin] = sh[rr][cc];
    }
    int rep = blockIdx.x & (NREP - 1);
    if (t < HH) {
        float s = 0.f, s2 = 0.f;
        for (int r = 0; r < 16; ++r) {
            float v = sh[r][t];
            s += v; s2 += v * v;
        }
        atomicAdd(&acc0[rep * HH + t], s);
        atomicAdd(&acc1[rep * HH + t], s2);
    }
}

// ---------------------------------------------------------------------------
// Kernel F: BN apply + head, one wave per row; sums the NREP stat replicas.
// ---------------------------------------------------------------------------
__global__ __launch_bounds__(256) void finalize(
    const float* __restrict__ h, const float* __restrict__ musum8,
    const float* __restrict__ varsum8, const float* __restrict__ gamma,
    const float* __restrict__ beta, const float* __restrict__ Wo,
    const float* __restrict__ bo, float* __restrict__ out_h,
    float* __restrict__ out_o)
{
    int t = threadIdx.x;
    int wv = t >> 6;
    int lane = t & 63;
    int i = blockIdx.x * 4 + wv;

    float2 mus = {0.f, 0.f}, vas = {0.f, 0.f};
    #pragma unroll
    for (int r = 0; r < NREP; ++r) {
        float2 a = ((const float2*)(musum8 + r * HH))[lane];
        float2 b = ((const float2*)(varsum8 + r * HH))[lane];
        mus.x += a.x; mus.y += a.y;
        vas.x += b.x; vas.y += b.y;
    }
    float2 ga  = ((const float2*)gamma)[lane];
    float2 be  = ((const float2*)beta)[lane];
    float mu0 = mus.x * (1.f / NN), mu1 = mus.y * (1.f / NN);
    float v0 = vas.x * (1.f / NN) - mu0 * mu0;
    float v1 = vas.y * (1.f / NN) - mu1 * mu1;
    float sc0 = ga.x / sqrtf(v0 + BN_EPS), sc1 = ga.y / sqrtf(v1 + BN_EPS);
    float sh0 = be.x - mu0 * sc0, sh1 = be.y - mu1 * sc1;

    float2 hv = ((const float2*)(h + (size_t)i * HH))[lane];
    float2 hb;
    hb.x = hv.x * sc0 + sh0;
    hb.y = hv.y * sc1 + sh1;
    ((float2*)(out_h + (size_t)i * HH))[lane] = hb;

    float2 w0 = ((const float2*)Wo)[lane];
    float2 w1 = ((const float2*)(Wo + HH))[lane];
    float2 w2 = ((const float2*)(Wo + 2 * HH))[lane];
    float p0 = hb.x * w0.x + hb.y * w0.y;
    float p1 = hb.x * w1.x + hb.y * w1.y;
    float p2 = hb.x * w2.x + hb.y * w2.y;
    for (int s = 32; s; s >>= 1) {
        p0 += __shfl_down(p0, s);
        p1 += __shfl_down(p1, s);
        p2 += __shfl_down(p2, s);
    }
    if (lane == 0) {
        out_o[(size_t)i * OUTD + 0] = p0 + bo[0];
        out_o[(size_t)i * OUTD + 1] = p1 + bo[1];
        out_o[(size_t)i * OUTD + 2] = p2 + bo[2];
    }
}

// ---------------------------------------------------------------------------
extern "C" void kernel_launch(void* const* d_in, const int* in_sizes, int n_in,
                              void* d_out, int out_size, void* d_ws, size_t ws_size,
                              hipStream_t stream)
{
    (void)in_sizes; (void)n_in; (void)out_size; (void)ws_size;
    const float* x_now = (const float*)d_in[0];
    const int*   sat   = (const int*)d_in[1];
    const float* Wl    = (const float*)d_in[2];
    const float* bl    = (const float*)d_in[3];
    const float* Wr    = (const float*)d_in[4];
    const float* gamma = (const float*)d_in[5];
    const float* beta  = (const float*)d_in[6];
    const float* Wo    = (const float*)d_in[7];
    const float* bo    = (const float*)d_in[8];

    ushortT* Wbf  = (ushortT*)d_ws;               // 65536 us [Wl0,Wl1,Wr0,Wr1]
    ushortT* x0bf = Wbf + 65536;                  // 524288 us
    ushortT* h1bf = x0bf + (size_t)NN * HH;       // 524288 us
    ushortT* mbf  = h1bf + (size_t)NN * HH;       // 524288 us (both layers)
    float* h2 = (float*)(mbf + (size_t)NN * HH);  // 524288 f
    float4* fn = (float4*)(h2 + (size_t)NN * HH);       // 4096 float4
    unsigned* mask = (unsigned*)((float*)fn + 4 * NN);  // 524288 words
    float* deg = (float*)(mask + (size_t)NN * 128);     // 4096
    // ---- zeroed accumulator region (one contiguous memset) ----
    int*   cnt   = (int*)(deg + NN);              // NREP*6 (reserve 64)
    float* S0rep = (float*)(cnt + 64);            // 6144
    float* S1rep = S0rep + NREP * NTYPES * HH;    // 6144
    float* mu8   = S1rep + NREP * NTYPES * HH;    // 1024
    float* var8  = mu8 + NREP * HH;               // 1024

    size_t zero_bytes = (64 + 2 * NREP * NTYPES * HH + 2 * NREP * HH)
                        * sizeof(float);
    hipMemsetAsync(cnt, 0, zero_bytes, stream);

    prep<<<264, 256, 0, stream>>>(x_now, sat, Wl, Wr, Wbf, x0bf, fn, cnt,
                                  S0rep);
    build_mask<<<NN / MROW, 256, 0, stream>>>(fn, sat, cnt, mask, deg);

    // layer 1
    gather_kernel<<<NN / 2, 256, 0, stream>>>(x0bf, mask, deg, S0rep, sat,
                                              mbf);
    gemm_l1<<<NN / 16, 256, 0, stream>>>(mbf, x0bf, Wbf, Wbf + 32768, bl, sat,
                                         h1bf, S1rep);

    // layer 2
    gather_kernel<<<NN / 2, 256, 0, stream>>>(h1bf, mask, deg, S1rep, sat,
                                              mbf);
    gemm_l2<<<NN / 16, 256, 0, stream>>>(mbf, h1bf, Wbf + 16384, Wbf + 49152,
                                         bl + HH, h2, mu8, var8);

    finalize<<<NN / 4, 256, 0, stream>>>(h2, mu8, var8, gamma, beta, Wo, bo,
                                         (float*)d_out, (float*)d_out + (size_t)NN * HH);
}